// Round 3
// baseline (1016.778 us; speedup 1.0000x reference)
//
#include <hip/hip_runtime.h>

// ---------------- bf16 helpers ----------------------------------------------
__device__ __forceinline__ float b2f(unsigned short u) {
    unsigned int v = ((unsigned int)u) << 16;
    return __builtin_bit_cast(float, v);
}
__device__ __forceinline__ unsigned short f2b(float f) {
    unsigned int x = __builtin_bit_cast(unsigned int, f);
    x += 0x7fffu + ((x >> 16) & 1u);   // round-to-nearest-even
    return (unsigned short)(x >> 16);
}

typedef short v8s __attribute__((ext_vector_type(8)));   // 8 bf16 = 4 VGPRs
typedef float v4f __attribute__((ext_vector_type(4)));   // MFMA accumulator

// ---------------- LayerNorm 1: fp32 x -> bf16 split (hi, lo) ----------------
__global__ __launch_bounds__(256) void ln1_kernel(
    const float* __restrict__ x, const float* __restrict__ g,
    const float* __restrict__ b, unsigned short* __restrict__ hhi,
    unsigned short* __restrict__ hlo)
{
    __shared__ float red[8];
    size_t row = blockIdx.x;
    const float4* xr = (const float4*)(x + row * 1024);
    int t = threadIdx.x;
    float4 v = xr[t];
    float s  = v.x + v.y + v.z + v.w;
    float s2 = v.x*v.x + v.y*v.y + v.z*v.z + v.w*v.w;
#pragma unroll
    for (int o = 32; o; o >>= 1) { s += __shfl_xor(s, o); s2 += __shfl_xor(s2, o); }
    int wid = t >> 6, lane = t & 63;
    if (!lane) { red[wid] = s; red[4 + wid] = s2; }
    __syncthreads();
    s  = red[0] + red[1] + red[2] + red[3];
    s2 = red[4] + red[5] + red[6] + red[7];
    float mu = s * (1.0f / 1024.0f);
    float var = s2 * (1.0f / 1024.0f) - mu * mu;
    float rs = rsqrtf(var + 1e-5f);
    float4 gv = ((const float4*)g)[t];
    float4 bv = ((const float4*)b)[t];
    float f0 = (v.x - mu) * rs * gv.x + bv.x;
    float f1 = (v.y - mu) * rs * gv.y + bv.y;
    float f2 = (v.z - mu) * rs * gv.z + bv.z;
    float f3 = (v.w - mu) * rs * gv.w + bv.w;
    ushort4 hi, lo;
    hi.x = f2b(f0); lo.x = f2b(f0 - b2f(hi.x));
    hi.y = f2b(f1); lo.y = f2b(f1 - b2f(hi.y));
    hi.z = f2b(f2); lo.z = f2b(f2 - b2f(hi.z));
    hi.w = f2b(f3); lo.w = f2b(f3 - b2f(hi.w));
    ((ushort4*)(hhi + row * 1024))[t] = hi;
    ((ushort4*)(hlo + row * 1024))[t] = lo;
}

// ---------------- LayerNorm 2: bf16 o -> bf16 oln ---------------------------
__global__ __launch_bounds__(256) void ln2_kernel(
    const unsigned short* __restrict__ o, const float* __restrict__ g,
    const float* __restrict__ b, unsigned short* __restrict__ out)
{
    __shared__ float red[8];
    size_t row = blockIdx.x;
    int t = threadIdx.x;
    ushort4 u = ((const ushort4*)(o + row * 1024))[t];
    float v0 = b2f(u.x), v1 = b2f(u.y), v2 = b2f(u.z), v3 = b2f(u.w);
    float s  = v0 + v1 + v2 + v3;
    float s2 = v0*v0 + v1*v1 + v2*v2 + v3*v3;
#pragma unroll
    for (int ofs = 32; ofs; ofs >>= 1) { s += __shfl_xor(s, ofs); s2 += __shfl_xor(s2, ofs); }
    int wid = t >> 6, lane = t & 63;
    if (!lane) { red[wid] = s; red[4 + wid] = s2; }
    __syncthreads();
    s  = red[0] + red[1] + red[2] + red[3];
    s2 = red[4] + red[5] + red[6] + red[7];
    float mu = s * (1.0f / 1024.0f);
    float var = s2 * (1.0f / 1024.0f) - mu * mu;
    float rs = rsqrtf(var + 1e-5f);
    float4 gv = ((const float4*)g)[t];
    float4 bv = ((const float4*)b)[t];
    ushort4 o4;
    o4.x = f2b((v0 - mu) * rs * gv.x + bv.x);
    o4.y = f2b((v1 - mu) * rs * gv.y + bv.y);
    o4.z = f2b((v2 - mu) * rs * gv.z + bv.z);
    o4.w = f2b((v3 - mu) * rs * gv.w + bv.w);
    ((ushort4*)(out + row * 1024))[t] = o4;
}

// ---------------- weights: fp32 [K][N] -> bf16 split B^T [N][K] -------------
// z=0,1,2 -> Wq,Wk,Wv into QKVh/QKVl; z=3 -> Wfc -> Wfch (hi only)
__global__ void conv_weights(
    const float* __restrict__ Wq, const float* __restrict__ Wk,
    const float* __restrict__ Wv, const float* __restrict__ Wfc,
    unsigned short* __restrict__ QKVh, unsigned short* __restrict__ QKVl,
    unsigned short* __restrict__ Wfch)
{
    int z = blockIdx.z;
    const float* W = (z == 0) ? Wq : (z == 1) ? Wk : (z == 2) ? Wv : Wfc;
    unsigned short* dh = (z < 3) ? (QKVh + (size_t)z * 1024 * 1024) : Wfch;
    unsigned short* dl = (z < 3) ? (QKVl + (size_t)z * 1024 * 1024) : nullptr;
    __shared__ float tile[32][33];
    int kt = blockIdx.y * 32, nt = blockIdx.x * 32;
    int tx = threadIdx.x, ty = threadIdx.y;   // (32,8)
#pragma unroll
    for (int i = 0; i < 32; i += 8)
        tile[ty + i][tx] = W[(size_t)(kt + ty + i) * 1024 + nt + tx];
    __syncthreads();
#pragma unroll
    for (int i = 0; i < 32; i += 8) {
        float val = tile[tx][ty + i];
        unsigned short hi = f2b(val);
        size_t idx = (size_t)(nt + ty + i) * 1024 + kt + tx;
        dh[idx] = hi;
        if (z < 3) dl[idx] = f2b(val - b2f(hi));
    }
}

// ---------------- bias concat [bq|bk|bv] ------------------------------------
__global__ void concat3(const float* __restrict__ a, const float* __restrict__ b,
                        const float* __restrict__ c, float* __restrict__ out)
{
    int i = threadIdx.x + blockIdx.x * 256;
    out[i] = (i < 1024) ? a[i] : (i < 2048) ? b[i - 1024] : c[i - 2048];
}

// ---------------- v transpose: v [nb*2048,1024] -> vT [nb][1024][2048] ------
__global__ void transpose_v(const unsigned short* __restrict__ v,
                            unsigned short* __restrict__ vT)
{
    int bz = blockIdx.z;
    __shared__ unsigned short tile[32][33];
    int st = blockIdx.y * 32, it = blockIdx.x * 32;
    int tx = threadIdx.x, ty = threadIdx.y;
#pragma unroll
    for (int i = 0; i < 32; i += 8)
        tile[ty + i][tx] = v[((size_t)bz * 2048 + st + ty + i) * 1024 + it + tx];
    __syncthreads();
#pragma unroll
    for (int i = 0; i < 32; i += 8)
        vT[((size_t)bz * 1024 + it + ty + i) * 2048 + st + tx] = tile[tx][ty + i];
}

// -------- row softmax: fp32 scores [2048] -> bf16 P IN PLACE over scores ----
// Safe: every thread's reads complete before the first reduction barrier;
// all writes happen after it.
__global__ __launch_bounds__(256) void softmax_kernel(float* __restrict__ S)
{
    __shared__ float red[8];
    size_t row = (size_t)blockIdx.z * 2048 + blockIdx.x;
    float* srow = S + row * 2048;
    const float4* sr = (const float4*)srow;
    int t = threadIdx.x;
    float4 a = sr[t], b = sr[t + 256];
    float m = fmaxf(fmaxf(fmaxf(a.x, a.y), fmaxf(a.z, a.w)),
                    fmaxf(fmaxf(b.x, b.y), fmaxf(b.z, b.w)));
#pragma unroll
    for (int o = 32; o; o >>= 1) m = fmaxf(m, __shfl_xor(m, o));
    int wid = t >> 6, lane = t & 63;
    if (!lane) red[wid] = m;
    __syncthreads();
    m = fmaxf(fmaxf(red[0], red[1]), fmaxf(red[2], red[3]));
    float e0 = __expf(a.x - m), e1 = __expf(a.y - m), e2 = __expf(a.z - m), e3 = __expf(a.w - m);
    float e4 = __expf(b.x - m), e5 = __expf(b.y - m), e6 = __expf(b.z - m), e7 = __expf(b.w - m);
    float s = e0 + e1 + e2 + e3 + e4 + e5 + e6 + e7;
#pragma unroll
    for (int o = 32; o; o >>= 1) s += __shfl_xor(s, o);
    if (!lane) red[4 + wid] = s;
    __syncthreads();
    s = red[4] + red[5] + red[6] + red[7];
    float inv = 1.0f / s;
    unsigned short* pr = (unsigned short*)srow;   // P in place, ld 4096 shorts
    ushort4 p0, p1;
    p0.x = f2b(e0 * inv); p0.y = f2b(e1 * inv); p0.z = f2b(e2 * inv); p0.w = f2b(e3 * inv);
    p1.x = f2b(e4 * inv); p1.y = f2b(e5 * inv); p1.z = f2b(e6 * inv); p1.w = f2b(e7 * inv);
    ((ushort4*)pr)[t] = p0;
    ((ushort4*)pr)[t + 256] = p1;
}

// ---------------- generic bf16 GEMM: C = A[M,K] * B^T[N,K] ------------------
// SPLIT=1: A,B are (hi,lo) bf16 pairs; acc = Ah*Bh + Ah*Bl + Al*Bh
// EPI 0: fp32 C = acc                          (scores)
// EPI 1: bf16 C = acc                          (o = PV)
// EPI 2: fp32 C = 2*(acc + bias + resid)       (final output)
// EPI 4: qkv routing: +bias, col<1024 -> split (C,Cl); <2048 -> split (C2,C2l);
//        else bf16 -> C3. Row-major ld 1024 each.
#define BM 128
#define BN 128
#define BK 32
#define LDK 40   // padded LDS leading dim (bf16 elems): stride 80B, 16B-aligned

template <int EPI, int SPLIT>
__global__ __launch_bounds__(256, 2) void gemm_bt(
    const unsigned short* __restrict__ Ah, const unsigned short* __restrict__ Al,
    int lda, long long sA,
    const unsigned short* __restrict__ Bh, const unsigned short* __restrict__ Bl,
    int ldb, long long sB,
    void* __restrict__ C, void* __restrict__ Cl,
    void* __restrict__ C2, void* __restrict__ C2l, void* __restrict__ C3,
    int ldc, long long sC,
    const float* __restrict__ bias, const float* __restrict__ resid, int K)
{
    __shared__ unsigned short As[(SPLIT + 1) * BM * LDK];
    __shared__ unsigned short Bs[(SPLIT + 1) * BN * LDK];

    int z = blockIdx.z;
    Ah += (size_t)z * sA;
    Bh += (size_t)z * sB;
    if (SPLIT) { Al += (size_t)z * sA; Bl += (size_t)z * sB; }
    size_t cbase = (size_t)z * sC;

    int m0 = blockIdx.y * BM, n0 = blockIdx.x * BN;
    int t = threadIdx.x;
    int wid = t >> 6, lane = t & 63;
    int wm = (wid >> 1) * 64, wn = (wid & 1) * 64;
    int lm = lane & 15, quad = lane >> 4;

    v4f acc[4][4] = {};

    int srow = t >> 2;          // 0..63
    int scol = (t & 3) * 8;     // 0,8,16,24

    for (int k0 = 0; k0 < K; k0 += BK) {
        size_t aoff = (size_t)(m0 + srow) * lda + k0 + scol;
        size_t boff = (size_t)(n0 + srow) * ldb + k0 + scol;
        uint4 a0 = *(const uint4*)(Ah + aoff);
        uint4 a1 = *(const uint4*)(Ah + aoff + (size_t)64 * lda);
        uint4 b0 = *(const uint4*)(Bh + boff);
        uint4 b1 = *(const uint4*)(Bh + boff + (size_t)64 * ldb);
        uint4 a0l, a1l, b0l, b1l;
        if (SPLIT) {
            a0l = *(const uint4*)(Al + aoff);
            a1l = *(const uint4*)(Al + aoff + (size_t)64 * lda);
            b0l = *(const uint4*)(Bl + boff);
            b1l = *(const uint4*)(Bl + boff + (size_t)64 * ldb);
        }
        __syncthreads();   // previous iter's LDS reads done
        *(uint4*)&As[srow * LDK + scol]        = a0;
        *(uint4*)&As[(srow + 64) * LDK + scol] = a1;
        *(uint4*)&Bs[srow * LDK + scol]        = b0;
        *(uint4*)&Bs[(srow + 64) * LDK + scol] = b1;
        if (SPLIT) {
            *(uint4*)&As[BM * LDK + srow * LDK + scol]        = a0l;
            *(uint4*)&As[BM * LDK + (srow + 64) * LDK + scol] = a1l;
            *(uint4*)&Bs[BN * LDK + srow * LDK + scol]        = b0l;
            *(uint4*)&Bs[BN * LDK + (srow + 64) * LDK + scol] = b1l;
        }
        __syncthreads();

        v8s afh[4], bfh[4], afl[4], bfl[4];
#pragma unroll
        for (int i = 0; i < 4; i++)
            afh[i] = *(const v8s*)&As[(wm + i * 16 + lm) * LDK + quad * 8];
#pragma unroll
        for (int j = 0; j < 4; j++)
            bfh[j] = *(const v8s*)&Bs[(wn + j * 16 + lm) * LDK + quad * 8];
        if (SPLIT) {
#pragma unroll
            for (int i = 0; i < 4; i++)
                afl[i] = *(const v8s*)&As[BM * LDK + (wm + i * 16 + lm) * LDK + quad * 8];
#pragma unroll
            for (int j = 0; j < 4; j++)
                bfl[j] = *(const v8s*)&Bs[BN * LDK + (wn + j * 16 + lm) * LDK + quad * 8];
        }
#pragma unroll
        for (int i = 0; i < 4; i++)
#pragma unroll
            for (int j = 0; j < 4; j++) {
                if (SPLIT) {
                    acc[i][j] = __builtin_amdgcn_mfma_f32_16x16x32_bf16(afl[i], bfh[j], acc[i][j], 0, 0, 0);
                    acc[i][j] = __builtin_amdgcn_mfma_f32_16x16x32_bf16(afh[i], bfl[j], acc[i][j], 0, 0, 0);
                }
                acc[i][j] = __builtin_amdgcn_mfma_f32_16x16x32_bf16(afh[i], bfh[j], acc[i][j], 0, 0, 0);
            }
    }

#pragma unroll
    for (int i = 0; i < 4; i++) {
#pragma unroll
        for (int j = 0; j < 4; j++) {
            int col = n0 + wn + j * 16 + lm;
#pragma unroll
            for (int r = 0; r < 4; r++) {
                int row = m0 + wm + i * 16 + quad * 4 + r;
                float v = acc[i][j][r];
                if (EPI == 0) {
                    ((float*)C)[cbase + (size_t)row * ldc + col] = v;
                } else if (EPI == 1) {
                    ((unsigned short*)C)[cbase + (size_t)row * ldc + col] = f2b(v);
                } else if (EPI == 2) {
                    v = 2.0f * (v + bias[col] + resid[(size_t)row * ldc + col]);
                    ((float*)C)[cbase + (size_t)row * ldc + col] = v;
                } else {  // EPI == 4: qkv routing, split q/k + plain v
                    v += bias[col];
                    size_t ridx = (size_t)row * 1024;
                    if (col < 1024) {
                        unsigned short hi = f2b(v);
                        ((unsigned short*)C)[ridx + col]  = hi;
                        ((unsigned short*)Cl)[ridx + col] = f2b(v - b2f(hi));
                    } else if (col < 2048) {
                        unsigned short hi = f2b(v);
                        ((unsigned short*)C2)[ridx + col - 1024]  = hi;
                        ((unsigned short*)C2l)[ridx + col - 1024] = f2b(v - b2f(hi));
                    } else {
                        ((unsigned short*)C3)[ridx + col - 2048] = f2b(v);
                    }
                }
            }
        }
    }
}

// ---------------- launch ----------------------------------------------------
extern "C" void kernel_launch(void* const* d_in, const int* in_sizes, int n_in,
                              void* d_out, int out_size, void* d_ws, size_t ws_size,
                              hipStream_t stream)
{
    const float* x   = (const float*)d_in[0];
    const float* Wq  = (const float*)d_in[1];
    const float* bq  = (const float*)d_in[2];
    const float* Wk  = (const float*)d_in[3];
    const float* bk  = (const float*)d_in[4];
    const float* Wv  = (const float*)d_in[5];
    const float* bv  = (const float*)d_in[6];
    const float* Wfc = (const float*)d_in[7];
    const float* bfc = (const float*)d_in[8];
    const float* g1  = (const float*)d_in[9];
    const float* b1  = (const float*)d_in[10];
    const float* g2  = (const float*)d_in[11];
    const float* b2  = (const float*)d_in[12];
    float* out = (float*)d_out;

    const int Mrows = 16384;           // B*S

    char* base = (char*)d_ws;
    size_t off = 0;
    auto alloc = [&](size_t bytes) -> void* {
        void* p = base + off;
        off += (bytes + 255) & ~(size_t)255;
        return p;
    };
    // ---- fixed allocations: ~148 MB ----
    unsigned short* QKVh = (unsigned short*)alloc(3072ull * 1024 * 2);
    unsigned short* QKVl = (unsigned short*)alloc(3072ull * 1024 * 2);
    unsigned short* Wfch = (unsigned short*)alloc(1024ull * 1024 * 2);
    float* bias_qkv      = (float*)alloc(3072ull * 4);
    unsigned short* hhi  = (unsigned short*)alloc((size_t)Mrows * 1024 * 2);
    unsigned short* hlo  = (unsigned short*)alloc((size_t)Mrows * 1024 * 2);
    unsigned short* o    = (unsigned short*)alloc((size_t)Mrows * 1024 * 2);
    unsigned short* oln  = (unsigned short*)alloc((size_t)Mrows * 1024 * 2);
    size_t fixed = off;

    // ---- per-batch scratch: qh,ql,kh,kl,v,vT = 24 MB; scores fp32 = 16 MB --
    const size_t perQK = 2048ull * 1024 * 2;     // 4 MB per plane per batch
    const size_t perS  = 2048ull * 2048 * 4;     // 16 MB per batch
    int nb = 8;
    while (nb > 1) {
        size_t need = fixed + (size_t)nb * 6 * perQK
                    + ((nb <= 2) ? 0 : (size_t)nb * perS);  // nb<=2: scores alias oln
        if (need <= ws_size) break;
        nb >>= 1;
    }
    unsigned short* qh   = (unsigned short*)alloc(perQK * nb);
    unsigned short* ql   = (unsigned short*)alloc(perQK * nb);
    unsigned short* kh   = (unsigned short*)alloc(perQK * nb);
    unsigned short* kl   = (unsigned short*)alloc(perQK * nb);
    unsigned short* vbuf = (unsigned short*)alloc(perQK * nb);
    unsigned short* vT   = (unsigned short*)alloc(perQK * nb);
    // scores: alias oln when it fits (oln is only written by LN2, after the loop)
    float* scores = (nb <= 2) ? (float*)oln : (float*)alloc(perS * nb);

    // 1) LN1 -> split h
    ln1_kernel<<<Mrows, 256, 0, stream>>>(x, g1, b1, hhi, hlo);
    // 2) weights -> split bf16 B^T, bias concat
    conv_weights<<<dim3(32, 32, 4), dim3(32, 8), 0, stream>>>(
        Wq, Wk, Wv, Wfc, QKVh, QKVl, Wfch);
    concat3<<<12, 256, 0, stream>>>(bq, bk, bv, bias_qkv);

    // 3) per-chunk attention pipeline
    for (int c = 0; c < 8; c += nb) {
        // 3a) QKV split GEMM for this chunk: M = nb*2048, N = 3072, K = 1024
        gemm_bt<4, 1><<<dim3(24, nb * 16, 1), 256, 0, stream>>>(
            hhi + (size_t)c * 2048 * 1024, hlo + (size_t)c * 2048 * 1024, 1024, 0,
            QKVh, QKVl, 1024, 0,
            qh, ql, kh, kl, vbuf, 0, 0, bias_qkv, nullptr, 1024);
        // 3b) v transpose -> vT [nb][1024][2048]
        transpose_v<<<dim3(32, 64, nb), dim3(32, 8), 0, stream>>>(vbuf, vT);
        // 3c) scores = q k^T (split, fp32 out)
        gemm_bt<0, 1><<<dim3(16, 16, nb), 256, 0, stream>>>(
            qh, ql, 1024, 2048LL * 1024,
            kh, kl, 1024, 2048LL * 1024,
            scores, nullptr, nullptr, nullptr, nullptr, 2048, 2048LL * 2048,
            nullptr, nullptr, 1024);
        // 3d) softmax in place (P bf16 into scores buffer, ld 4096 shorts)
        softmax_kernel<<<dim3(2048, 1, nb), 256, 0, stream>>>(scores);
        // 3e) o = P vT
        gemm_bt<1, 0><<<dim3(8, 16, nb), 256, 0, stream>>>(
            (const unsigned short*)scores, nullptr, 4096, 2048LL * 4096,
            vT, nullptr, 2048, 1024LL * 2048,
            o + (size_t)c * 2048 * 1024, nullptr, nullptr, nullptr, nullptr,
            1024, 2048LL * 1024,
            nullptr, nullptr, 2048);
    }
    // 4) LN2
    ln2_kernel<<<Mrows, 256, 0, stream>>>(o, g2, b2, oln);
    // 5) final GEMM + bias + residual + doubling
    gemm_bt<2, 0><<<dim3(8, 128, 1), 256, 0, stream>>>(
        oln, nullptr, 1024, 0, Wfch, nullptr, 1024, 0,
        out, nullptr, nullptr, nullptr, nullptr, 1024, 0, bfc, x, 1024);
}

// Round 5
// 645.602 us; speedup vs baseline: 1.5749x; 1.5749x over previous
//
#include <hip/hip_runtime.h>

// ---------------- fp16 helpers ----------------------------------------------
__device__ __forceinline__ unsigned short f2h(float f) {
    _Float16 h = (_Float16)f;                       // v_cvt_f16_f32, RNE
    return __builtin_bit_cast(unsigned short, h);
}
__device__ __forceinline__ float h2f(unsigned short u) {
    return (float)__builtin_bit_cast(_Float16, u);
}

typedef _Float16 v8h __attribute__((ext_vector_type(8)));  // 8 f16 = 4 VGPRs
typedef float    v4f __attribute__((ext_vector_type(4)));  // MFMA accumulator

// ---------------- LayerNorm 1: fp32 x -> fp16 h  (row = 1024) ---------------
__global__ __launch_bounds__(256) void ln1_kernel(
    const float* __restrict__ x, const float* __restrict__ g,
    const float* __restrict__ b, unsigned short* __restrict__ h)
{
    __shared__ float red[8];
    size_t row = blockIdx.x;
    const float4* xr = (const float4*)(x + row * 1024);
    int t = threadIdx.x;
    float4 v = xr[t];
    float s  = v.x + v.y + v.z + v.w;
    float s2 = v.x*v.x + v.y*v.y + v.z*v.z + v.w*v.w;
#pragma unroll
    for (int o = 32; o; o >>= 1) { s += __shfl_xor(s, o); s2 += __shfl_xor(s2, o); }
    int wid = t >> 6, lane = t & 63;
    if (!lane) { red[wid] = s; red[4 + wid] = s2; }
    __syncthreads();
    s  = red[0] + red[1] + red[2] + red[3];
    s2 = red[4] + red[5] + red[6] + red[7];
    float mu = s * (1.0f / 1024.0f);
    float var = s2 * (1.0f / 1024.0f) - mu * mu;
    float rs = rsqrtf(var + 1e-5f);
    float4 gv = ((const float4*)g)[t];
    float4 bv = ((const float4*)b)[t];
    ushort4 o4;
    o4.x = f2h((v.x - mu) * rs * gv.x + bv.x);
    o4.y = f2h((v.y - mu) * rs * gv.y + bv.y);
    o4.z = f2h((v.z - mu) * rs * gv.z + bv.z);
    o4.w = f2h((v.w - mu) * rs * gv.w + bv.w);
    ((ushort4*)(h + row * 1024))[t] = o4;
}

// -------- LayerNorm 2 IN PLACE: fp16 o -> fp16 o ----------------------------
// Safe: one block per row; every thread reads its row slice into registers
// before the reduction barriers; writes happen after. No cross-block sharing.
__global__ __launch_bounds__(256) void ln2_kernel(
    unsigned short* __restrict__ o, const float* __restrict__ g,
    const float* __restrict__ b)
{
    __shared__ float red[8];
    size_t row = blockIdx.x;
    int t = threadIdx.x;
    ushort4 u = ((const ushort4*)(o + row * 1024))[t];
    float v0 = h2f(u.x), v1 = h2f(u.y), v2 = h2f(u.z), v3 = h2f(u.w);
    float s  = v0 + v1 + v2 + v3;
    float s2 = v0*v0 + v1*v1 + v2*v2 + v3*v3;
#pragma unroll
    for (int ofs = 32; ofs; ofs >>= 1) { s += __shfl_xor(s, ofs); s2 += __shfl_xor(s2, ofs); }
    int wid = t >> 6, lane = t & 63;
    if (!lane) { red[wid] = s; red[4 + wid] = s2; }
    __syncthreads();
    s  = red[0] + red[1] + red[2] + red[3];
    s2 = red[4] + red[5] + red[6] + red[7];
    float mu = s * (1.0f / 1024.0f);
    float var = s2 * (1.0f / 1024.0f) - mu * mu;
    float rs = rsqrtf(var + 1e-5f);
    float4 gv = ((const float4*)g)[t];
    float4 bv = ((const float4*)b)[t];
    ushort4 o4;
    o4.x = f2h((v0 - mu) * rs * gv.x + bv.x);
    o4.y = f2h((v1 - mu) * rs * gv.y + bv.y);
    o4.z = f2h((v2 - mu) * rs * gv.z + bv.z);
    o4.w = f2h((v3 - mu) * rs * gv.w + bv.w);
    ((ushort4*)(o + row * 1024))[t] = o4;
}

// ---------------- weights: fp32 [K][N] -> fp16 B^T [N][K] -------------------
// z=0,1,2 -> Wq,Wk,Wv into QKVt rows [z*1024, (z+1)*1024); z=3 -> Wfc -> Wfct
__global__ void conv_weights(
    const float* __restrict__ Wq, const float* __restrict__ Wk,
    const float* __restrict__ Wv, const float* __restrict__ Wfc,
    unsigned short* __restrict__ QKVt, unsigned short* __restrict__ Wfct)
{
    int z = blockIdx.z;
    const float* W = (z == 0) ? Wq : (z == 1) ? Wk : (z == 2) ? Wv : Wfc;
    unsigned short* dst = (z < 3) ? (QKVt + (size_t)z * 1024 * 1024) : Wfct;
    __shared__ float tile[32][33];
    int kt = blockIdx.y * 32, nt = blockIdx.x * 32;
    int tx = threadIdx.x, ty = threadIdx.y;   // (32,8)
#pragma unroll
    for (int i = 0; i < 32; i += 8)
        tile[ty + i][tx] = W[(size_t)(kt + ty + i) * 1024 + nt + tx];
    __syncthreads();
#pragma unroll
    for (int i = 0; i < 32; i += 8)
        dst[(size_t)(nt + ty + i) * 1024 + kt + tx] = f2h(tile[tx][ty + i]);
}

// ---------------- bias concat [bq|bk|bv] ------------------------------------
__global__ void concat3(const float* __restrict__ a, const float* __restrict__ b,
                        const float* __restrict__ c, float* __restrict__ out)
{
    int i = threadIdx.x + blockIdx.x * 256;
    out[i] = (i < 1024) ? a[i] : (i < 2048) ? b[i - 1024] : c[i - 2048];
}

// ------- v transpose (per chunk): qkv v-slice [s][i] -> vT [bz][i][s] -------
// qkv pointer is pre-offset to the chunk's first batch.
__global__ void transpose_v(const unsigned short* __restrict__ qkv,
                            unsigned short* __restrict__ vT)
{
    int bz = blockIdx.z;
    __shared__ unsigned short tile[32][33];
    int st = blockIdx.y * 32, it = blockIdx.x * 32;
    int tx = threadIdx.x, ty = threadIdx.y;
#pragma unroll
    for (int i = 0; i < 32; i += 8)
        tile[ty + i][tx] = qkv[((size_t)bz * 2048 + st + ty + i) * 3072 + 2048 + it + tx];
    __syncthreads();
#pragma unroll
    for (int i = 0; i < 32; i += 8)
        vT[((size_t)bz * 1024 + it + ty + i) * 2048 + st + tx] = tile[tx][ty + i];
}

// -------- row softmax: fp32 scores [2048] -> fp16 P IN PLACE over scores ----
// Safe: all reads complete before the first reduction barrier; writes after.
__global__ __launch_bounds__(256) void softmax_kernel(float* __restrict__ S)
{
    __shared__ float red[8];
    size_t row = (size_t)blockIdx.z * 2048 + blockIdx.x;
    float* srow = S + row * 2048;
    const float4* sr = (const float4*)srow;
    int t = threadIdx.x;
    float4 a = sr[t], b = sr[t + 256];
    float m = fmaxf(fmaxf(fmaxf(a.x, a.y), fmaxf(a.z, a.w)),
                    fmaxf(fmaxf(b.x, b.y), fmaxf(b.z, b.w)));
#pragma unroll
    for (int o = 32; o; o >>= 1) m = fmaxf(m, __shfl_xor(m, o));
    int wid = t >> 6, lane = t & 63;
    if (!lane) red[wid] = m;
    __syncthreads();
    m = fmaxf(fmaxf(red[0], red[1]), fmaxf(red[2], red[3]));
    float e0 = __expf(a.x - m), e1 = __expf(a.y - m), e2 = __expf(a.z - m), e3 = __expf(a.w - m);
    float e4 = __expf(b.x - m), e5 = __expf(b.y - m), e6 = __expf(b.z - m), e7 = __expf(b.w - m);
    float s = e0 + e1 + e2 + e3 + e4 + e5 + e6 + e7;
#pragma unroll
    for (int o = 32; o; o >>= 1) s += __shfl_xor(s, o);
    if (!lane) red[4 + wid] = s;
    __syncthreads();
    s = red[4] + red[5] + red[6] + red[7];
    float inv = 1.0f / s;
    unsigned short* pr = (unsigned short*)srow;   // P fp16 in place, row stride 4096 halfs
    ushort4 p0, p1;
    p0.x = f2h(e0 * inv); p0.y = f2h(e1 * inv); p0.z = f2h(e2 * inv); p0.w = f2h(e3 * inv);
    p1.x = f2h(e4 * inv); p1.y = f2h(e5 * inv); p1.z = f2h(e6 * inv); p1.w = f2h(e7 * inv);
    ((ushort4*)pr)[t] = p0;
    ((ushort4*)pr)[t + 256] = p1;
}

// ---------------- fp16 GEMM: C = A[M,K] * B^T[N,K] --------------------------
// EPI 0: fp32 C = acc                          (scores)
// EPI 1: fp16 C = acc (+bias if non-null)      (qkv, o = PV)
// EPI 2: fp32 C = 2*(acc + bias + resid)       (final output)
#define BM 128
#define BN 128
#define BK 32
#define LDK 40   // padded LDS leading dim (fp16 elems): stride 80B, 16B-aligned

template <int EPI>
__global__ __launch_bounds__(256, 2) void gemm_f16(
    const unsigned short* __restrict__ A, int lda, long long sA,
    const unsigned short* __restrict__ B, int ldb, long long sB,
    void* __restrict__ C, int ldc, long long sC,
    const float* __restrict__ bias, const float* __restrict__ resid, int K)
{
    __shared__ unsigned short As[BM * LDK];
    __shared__ unsigned short Bs[BN * LDK];

    int z = blockIdx.z;
    A += (size_t)z * sA;
    B += (size_t)z * sB;
    size_t cbase = (size_t)z * sC;

    int m0 = blockIdx.y * BM, n0 = blockIdx.x * BN;
    int t = threadIdx.x;
    int wid = t >> 6, lane = t & 63;
    int wm = (wid >> 1) * 64, wn = (wid & 1) * 64;
    int lm = lane & 15, quad = lane >> 4;

    v4f acc[4][4] = {};

    int srow = t >> 2;          // 0..63
    int scol = (t & 3) * 8;     // 0,8,16,24

    for (int k0 = 0; k0 < K; k0 += BK) {
        size_t aoff = (size_t)(m0 + srow) * lda + k0 + scol;
        size_t boff = (size_t)(n0 + srow) * ldb + k0 + scol;
        uint4 a0 = *(const uint4*)(A + aoff);
        uint4 a1 = *(const uint4*)(A + aoff + (size_t)64 * lda);
        uint4 b0 = *(const uint4*)(B + boff);
        uint4 b1 = *(const uint4*)(B + boff + (size_t)64 * ldb);
        __syncthreads();   // previous iter's LDS reads done
        *(uint4*)&As[srow * LDK + scol]        = a0;
        *(uint4*)&As[(srow + 64) * LDK + scol] = a1;
        *(uint4*)&Bs[srow * LDK + scol]        = b0;
        *(uint4*)&Bs[(srow + 64) * LDK + scol] = b1;
        __syncthreads();

        v8h af[4], bf[4];
#pragma unroll
        for (int i = 0; i < 4; i++)
            af[i] = *(const v8h*)&As[(wm + i * 16 + lm) * LDK + quad * 8];
#pragma unroll
        for (int j = 0; j < 4; j++)
            bf[j] = *(const v8h*)&Bs[(wn + j * 16 + lm) * LDK + quad * 8];
#pragma unroll
        for (int i = 0; i < 4; i++)
#pragma unroll
            for (int j = 0; j < 4; j++)
                acc[i][j] = __builtin_amdgcn_mfma_f32_16x16x32_f16(af[i], bf[j], acc[i][j], 0, 0, 0);
    }

#pragma unroll
    for (int i = 0; i < 4; i++) {
#pragma unroll
        for (int j = 0; j < 4; j++) {
            int col = n0 + wn + j * 16 + lm;
#pragma unroll
            for (int r = 0; r < 4; r++) {
                int row = m0 + wm + i * 16 + quad * 4 + r;
                float v = acc[i][j][r];
                size_t idx = cbase + (size_t)row * ldc + col;
                if (EPI == 0) {
                    ((float*)C)[idx] = v;
                } else if (EPI == 1) {
                    if (bias) v += bias[col];
                    ((unsigned short*)C)[idx] = f2h(v);
                } else {
                    v = 2.0f * (v + bias[col] + resid[(size_t)row * ldc + col]);
                    ((float*)C)[idx] = v;
                }
            }
        }
    }
}

// ---------------- launch ----------------------------------------------------
extern "C" void kernel_launch(void* const* d_in, const int* in_sizes, int n_in,
                              void* d_out, int out_size, void* d_ws, size_t ws_size,
                              hipStream_t stream)
{
    const float* x   = (const float*)d_in[0];
    const float* Wq  = (const float*)d_in[1];
    const float* bq  = (const float*)d_in[2];
    const float* Wk  = (const float*)d_in[3];
    const float* bk  = (const float*)d_in[4];
    const float* Wv  = (const float*)d_in[5];
    const float* bv  = (const float*)d_in[6];
    const float* Wfc = (const float*)d_in[7];
    const float* bfc = (const float*)d_in[8];
    const float* g1  = (const float*)d_in[9];
    const float* b1  = (const float*)d_in[10];
    const float* g2  = (const float*)d_in[11];
    const float* b2  = (const float*)d_in[12];
    float* out = (float*)d_out;

    const int Mrows = 16384;           // B*S

    char* base = (char*)d_ws;
    size_t off = 0;
    auto alloc = [&](size_t bytes) -> void* {
        void* p = base + off;
        off += (bytes + 255) & ~(size_t)255;
        return p;
    };
    // ---- fixed: ~142.7 MB ----
    unsigned short* QKVt = (unsigned short*)alloc(3072ull * 1024 * 2);       //   6.3 MB
    unsigned short* Wfct = (unsigned short*)alloc(1024ull * 1024 * 2);       //   2.1 MB
    float* bias_qkv      = (float*)alloc(3072ull * 4);
    unsigned short* h    = (unsigned short*)alloc((size_t)Mrows * 1024 * 2); //  33.6 MB (reused as o/oln)
    unsigned short* qkv  = (unsigned short*)alloc((size_t)Mrows * 3072 * 2); // 100.7 MB
    size_t fixed = off;

    // ---- per-chunk: vT 4.2 MB + scores 16.8 MB per batch; adapt NB ----
    const size_t perVT = 2048ull * 1024 * 2;
    const size_t perS  = 2048ull * 2048 * 4;
    int NB = 8;
    while (NB > 1 && fixed + (size_t)NB * (perVT + perS) > ws_size) NB >>= 1;
    unsigned short* vT = (unsigned short*)alloc(perVT * NB);
    float* scores      = (float*)alloc(perS * NB);
    unsigned short* o  = h;            // h dead after QKV GEMM; LN2 runs in place

    // 1) LN1 -> fp16 h
    ln1_kernel<<<Mrows, 256, 0, stream>>>(x, g1, b1, h);
    // 2) weights -> fp16 B^T, bias concat
    conv_weights<<<dim3(32, 32, 4), dim3(32, 8), 0, stream>>>(Wq, Wk, Wv, Wfc, QKVt, Wfct);
    concat3<<<12, 256, 0, stream>>>(bq, bk, bv, bias_qkv);
    // 3) fused QKV GEMM: [16384,1024] x [3072,1024]^T -> fp16 [16384,3072]
    gemm_f16<1><<<dim3(24, 128, 1), 256, 0, stream>>>(
        h, 1024, 0, QKVt, 1024, 0, qkv, 3072, 0, bias_qkv, nullptr, 1024);
    // 4) attention, NB batches per chunk (vT + scores buffers reused)
    for (int c = 0; c < 8; c += NB) {
        const size_t bofs = (size_t)c * 2048 * 3072;
        // v transpose for this chunk -> vT [NB][1024][2048]
        transpose_v<<<dim3(32, 64, NB), dim3(32, 8), 0, stream>>>(qkv + bofs, vT);
        // scores = q k^T (fp32 out)
        gemm_f16<0><<<dim3(16, 16, NB), 256, 0, stream>>>(
            qkv + bofs, 3072, 2048LL * 3072,
            qkv + 1024 + bofs, 3072, 2048LL * 3072,
            scores, 2048, 2048LL * 2048, nullptr, nullptr, 1024);
        // softmax in place (P fp16, row stride 4096 halfs)
        softmax_kernel<<<dim3(2048, 1, NB), 256, 0, stream>>>(scores);
        // o = P vT
        gemm_f16<1><<<dim3(8, 16, NB), 256, 0, stream>>>(
            (const unsigned short*)scores, 4096, 2048LL * 4096,
            vT, 2048, 1024LL * 2048,
            o + (size_t)c * 2048 * 1024, 1024, 2048LL * 1024,
            nullptr, nullptr, 2048);
    }
    // 5) LN2 in place on o
    ln2_kernel<<<Mrows, 256, 0, stream>>>(o, g2, b2);
    // 6) final GEMM + bias + residual + doubling
    gemm_f16<2><<<dim3(8, 128, 1), 256, 0, stream>>>(
        o, 1024, 0, Wfct, 1024, 0, out, 1024, 0, bfc, x, 1024);
}